// Round 19
// baseline (179.646 us; speedup 1.0000x reference)
//
#include <hip/hip_runtime.h>
#include <math.h>

typedef unsigned int uint32;
typedef unsigned short u16;

#if __has_builtin(__builtin_amdgcn_exp2f)
#define EXP2F(x) __builtin_amdgcn_exp2f(x)
#else
#define EXP2F(x) exp2f(x)
#endif

#define LROWS 64            // rows per linear block (4 waves x 16)
#define CHUNK 8192
#define CHUNK_SHIFT 13
#define NBUCK_MAX 512       // >= (N+127)>>7
#define LPB 384             // lists per bucket = 128 dsts * 3 hops

typedef __attribute__((ext_vector_type(8))) short bf16x8;
typedef __attribute__((ext_vector_type(4))) float f32x4;

__device__ __forceinline__ u16 f2bf(float f) {  // RNE
    uint32 u = __float_as_uint(f);
    u += 0x7fffu + ((u >> 16) & 1u);
    return (u16)(u >> 16);
}
__device__ __forceinline__ float bflo(uint32 v) { return __uint_as_float(v << 16); }
// hi bf16 with junk low mantissa bits: rel err < 2^-16, exponent untouched (no NaN/Inf)
__device__ __forceinline__ float bfhij(uint32 v) { return __uint_as_float(v); }

template<int PAT>
__device__ __forceinline__ float swz(float v) {  // ds_swizzle xor within 32 lanes
    return __int_as_float(__builtin_amdgcn_ds_swizzle(__float_as_int(v), PAT));
}
// DPP-fused cross-lane add. 0xB1=quad_perm[1,0,3,2] (exact xor1) and
// 0x4E=quad_perm[2,3,0,1] (exact xor2) are exact permutations -> always valid.
// Mirror controls are NOT exact xors; only usable on subgroup-homogeneous data
// (r14 lesson). This kernel uses only the two exact quad perms.
template<int CTRL>
__device__ __forceinline__ float dppadd(float v) {
    int r = __builtin_amdgcn_update_dpp(0, __float_as_int(v), CTRL, 0xF, 0xF, true);
    return v + __int_as_float(r);
}

// decode edge t -> (hop, src, dst); synthetic t>=3E are hop-0 self-loops
__device__ __forceinline__ void edge_decode(
    int t, int E, const int* __restrict__ e0, const int* __restrict__ e1,
    const int* __restrict__ e2, int& hop, int& src, int& dst)
{
    if (t < E)          { hop = 0; src = e0[t];         dst = e0[E + t]; }
    else if (t < 2 * E) { hop = 1; src = e1[t - E];     dst = e1[t]; }
    else if (t < 3 * E) { hop = 2; src = e2[t - 2 * E]; dst = e2[t - E]; }
    else                { hop = 0; src = t - 3 * E;     dst = src; }
}

// ---- wprep: permute [wl|wr] into MFMA B-fragment order, bf16 -----------------
__global__ __launch_bounds__(256) void wprep(
    const float* __restrict__ wl, const float* __restrict__ wr, u16* __restrict__ wfrag)
{
    int ct = blockIdx.x;            // 0..15 col-tile
    int ks = threadIdx.x >> 6;      // 0..3 K-step
    int lane = threadIdx.x & 63;
    int g = lane >> 4, rr = lane & 15;
    int c = ct * 16 + rr;
    const float* w = (c < 128) ? wl : wr;
    int cc = c & 127;
    u16* o = wfrag + (((size_t)ct * 4 + ks) * 64 + lane) * 8;
#pragma unroll
    for (int i = 0; i < 8; ++i) {
        int k = ks * 32 + g * 4 + (i & 3) + ((i >> 2) << 4);
        o[i] = f2bf(w[k * 128 + cc]);
    }
}

// ---- fused: [0,LB) MFMA-linear+gate blocks; [LB,LB+NBLKA) bucket-hist blocks -
__global__ __launch_bounds__(256) void fused_pre(
    const float* __restrict__ x, const u16* __restrict__ wfrag,
    const float* __restrict__ bl, const float* __restrict__ br,
    const float* __restrict__ gw, const float* __restrict__ gb,
    u16* __restrict__ xl, u16* __restrict__ xr, float* __restrict__ gate4,
    const int* __restrict__ e0, const int* __restrict__ e1, const int* __restrict__ e2,
    int* __restrict__ hist,
    int N, int E, int T, int LB, int NBUCK)
{
    __shared__ float4 sx[LROWS][32];
    __shared__ float gbuf[LROWS][3];
    __shared__ int lhist[NBUCK_MAX];

    if ((int)blockIdx.x >= LB) {                 // ---- pass A1: pure bucket histogram
        int blk = (int)blockIdx.x - LB;
        int t0 = blk << CHUNK_SHIFT;
        for (int j = threadIdx.x; j < NBUCK; j += 256) lhist[j] = 0;
        __syncthreads();
        for (int it = 0; it < CHUNK / 256; ++it) {
            int t = t0 + it * 256 + (int)threadIdx.x;
            if (t < T) {
                int dst;
                if (t < E)          dst = e0[E + t];
                else if (t < 2 * E) dst = e1[t];
                else if (t < 3 * E) dst = e2[t - E];
                else                dst = t - 3 * E;
                atomicAdd(&lhist[dst >> 7], 1);  // non-returning -> ds_add
            }
        }
        __syncthreads();
        for (int j = threadIdx.x; j < NBUCK; j += 256)
            hist[(size_t)blk * NBUCK + j] = lhist[j];
        return;
    }
    // ---- linear via MFMA + gate ----
    int t = threadIdx.x;
    int r0 = blockIdx.x * LROWS;
    int nr = min(LROWS, N - r0);
    {
        const float4* xi = (const float4*)(x + (size_t)r0 * 128);
        for (int i = t; i < nr * 32; i += 256) ((float4*)sx)[i] = xi[i];
    }
    __syncthreads();
    int wv = t >> 6, lane = t & 63;
    int g = lane >> 4, rr = lane & 15;
    // A fragments: row = wv*16 + (lane&15)  [m89-verified M mapping]
    bf16x8 afr[4];
    {
        const float4* xrow = sx[wv * 16 + rr];
#pragma unroll
        for (int ks = 0; ks < 4; ++ks) {
            float4 u = xrow[ks * 8 + g];       // k = ks*32 + g*4 + 0..3
            float4 v = xrow[ks * 8 + 4 + g];   // k = ks*32 + 16 + g*4 + 0..3
            union { u16 h[8]; bf16x8 v8; } pk;
            pk.h[0] = f2bf(u.x); pk.h[1] = f2bf(u.y);
            pk.h[2] = f2bf(u.z); pk.h[3] = f2bf(u.w);
            pk.h[4] = f2bf(v.x); pk.h[5] = f2bf(v.y);
            pk.h[6] = f2bf(v.z); pk.h[7] = f2bf(v.w);
            afr[ks] = pk.v8;
        }
    }
    const bf16x8* wfp = (const bf16x8*)wfrag;
    for (int ct = 0; ct < 16; ++ct) {
        f32x4 acc = {0.f, 0.f, 0.f, 0.f};
#pragma unroll
        for (int ks = 0; ks < 4; ++ks) {
            bf16x8 bf = wfp[((ct * 4 + ks) << 6) + lane];
            acc = __builtin_amdgcn_mfma_f32_16x16x32_bf16(afr[ks], bf, acc, 0, 0, 0);
        }
        int c = ct * 16 + rr;
        float bv = (ct < 8) ? bl[c] : br[c - 128];
        u16* ob = (ct < 8) ? xl : xr;
        int cc = c & 127;
#pragma unroll
        for (int i = 0; i < 4; ++i) {          // D: row=(lane>>4)*4+i, col=lane&15
            int row = wv * 16 + g * 4 + i;
            if (row < nr)
                ob[(size_t)(r0 + row) * 128 + cc] = f2bf(acc[i] + bv);
        }
    }
    // gate (fp32 from LDS, unchanged)
    if (t < nr * 3) {
        int r = t / 3, k = t - 3 * r;
        float s = 0.f;
        const float4* xrow = sx[r];
#pragma unroll 4
        for (int i = 0; i < 32; ++i) {
            float4 v = xrow[i];
            s += v.x * gw[(4 * i + 0) * 3 + k] + v.y * gw[(4 * i + 1) * 3 + k]
               + v.z * gw[(4 * i + 2) * 3 + k] + v.w * gw[(4 * i + 3) * 3 + k];
        }
        gbuf[r][k] = s + gb[k];
    }
    __syncthreads();
    if (t < nr) {
        float s0 = gbuf[t][0], s1 = gbuf[t][1], s2 = gbuf[t][2];
        float mx = fmaxf(s0, fmaxf(s1, s2));
        float e0v = __expf(s0 - mx), e1v = __expf(s1 - mx), e2v = __expf(s2 - mx);
        float inv = 1.f / (e0v + e1v + e2v);
        *(float4*)(gate4 + (size_t)(r0 + t) * 4) = make_float4(e0v * inv, e1v * inv, e2v * inv, 0.f);
    }
}

// ---- scans over hist in bin-major order (i -> (bin=i/NBLKA, blk=i%NBLKA)) ----
__global__ __launch_bounds__(1024) void scan1h(const int* __restrict__ hist, int MH,
                                               int NBLKA, int NBUCK,
                                               int* __restrict__ histS, int* __restrict__ partials) {
    __shared__ int s[1024];
    int t = threadIdx.x;
    int i = blockIdx.x * 1024 + t;
    int v = 0;
    if (i < MH) {
        int bin = (int)((uint32)i / (uint32)NBLKA);
        int blk = i - bin * NBLKA;
        v = hist[(size_t)blk * NBUCK + bin];
    }
    s[t] = v;
    __syncthreads();
    for (int o = 1; o < 1024; o <<= 1) {
        int u = (t >= o) ? s[t - o] : 0;
        __syncthreads();
        s[t] += u;
        __syncthreads();
    }
    if (i < MH) histS[i] = s[t] - v;
    if (t == 1023) partials[blockIdx.x] = s[1023];
}

__global__ __launch_bounds__(1024) void scan2(int* __restrict__ partials, int G) {
    __shared__ int s[1024];
    int t = threadIdx.x;
    int v = (t < G) ? partials[t] : 0;
    s[t] = v;
    __syncthreads();
    for (int o = 1; o < 1024; o <<= 1) {
        int u = (t >= o) ? s[t - o] : 0;
        __syncthreads();
        s[t] += u;
        __syncthreads();
    }
    if (t < G) partials[t] = s[t] - v;
}

// ---- pass A2: LDS-stage chunk sorted by bucket (self-ranked), coalesced flush -
__global__ __launch_bounds__(512) void passA2(
    const int* __restrict__ e0, const int* __restrict__ e1, const int* __restrict__ e2,
    int E, int T, int NBLKA, int NBUCK,
    const int* __restrict__ hist, const int* __restrict__ histS,
    const int* __restrict__ partials,
    uint32* __restrict__ pairs)
{
    __shared__ int lscan[512];
    __shared__ int gbase[512];
    __shared__ uint32 lp[CHUNK];
    __shared__ u16 lb[CHUNK];
    int blk = blockIdx.x, tid = threadIdx.x;
    int t0 = blk << CHUNK_SHIFT;
    int vc = min(CHUNK, T - t0);
    int c = (tid < NBUCK) ? hist[(size_t)blk * NBUCK + tid] : 0;
    lscan[tid] = c;
    __syncthreads();
    for (int o = 1; o < 512; o <<= 1) {
        int u = (tid >= o) ? lscan[tid - o] : 0;
        __syncthreads();
        lscan[tid] += u;
        __syncthreads();
    }
    int excl = lscan[tid] - c;
    lscan[tid] = excl;                    // becomes the placement cursor
    if (tid < NBUCK) {
        int k = tid * NBLKA + blk;
        gbase[tid] = histS[k] + partials[k >> 10] - excl;
    }
    __syncthreads();
    for (int it = 0; it < CHUNK / 512; ++it) {
        int t = t0 + it * 512 + tid;
        if (t < T) {
            int hop, src, dst;
            edge_decode(t, E, e0, e1, e2, hop, src, dst);
            int bin = dst >> 7;
            int j = atomicAdd(&lscan[bin], 1);   // self-rank (order need not match A1)
            lp[j] = (uint32)src | ((uint32)((dst & 127) * 3 + hop) << 16);
            lb[j] = (u16)bin;
        }
    }
    __syncthreads();
    for (int j = tid; j < vc; j += 512)
        pairs[gbase[lb[j]] + j] = lp[j];
}

// ---- pass B: per-bucket counting sort -> offsets + csr (LDS atomics only) ----
__global__ __launch_bounds__(512) void passB(
    const uint32* __restrict__ pairs, const int* __restrict__ histS,
    const int* __restrict__ partials, u16* __restrict__ csr, int* __restrict__ offsets,
    int T, int M, int NBLKA, int NBUCK) {
    __shared__ int cnt[LPB];
    __shared__ int scn[512];
    int b = blockIdx.x;
    int tid = threadIdx.x;
    int k0 = b * NBLKA;
    int bbase = histS[k0] + partials[k0 >> 10];
    int bend;
    if (b == NBUCK - 1) bend = T;
    else { int k1 = k0 + NBLKA; bend = histS[k1] + partials[k1 >> 10]; }
    if (b == 0 && tid == 0) offsets[M] = T;

    if (tid < LPB) cnt[tid] = 0;
    __syncthreads();
    for (int p = bbase + tid; p < bend; p += 512)
        atomicAdd(&cnt[pairs[p] >> 16], 1);
    __syncthreads();
    int c = (tid < LPB) ? cnt[tid] : 0;
    scn[tid] = c;
    __syncthreads();
    for (int o = 1; o < 512; o <<= 1) {
        int u = (tid >= o) ? scn[tid - o] : 0;
        __syncthreads();
        scn[tid] += u;
        __syncthreads();
    }
    int excl = scn[tid] - c;
    int nlists = min(LPB, M - b * LPB);
    if (tid < nlists) offsets[b * LPB + tid] = bbase + excl;
    __syncthreads();
    if (tid < LPB) cnt[tid] = excl;          // cursor
    __syncthreads();
    for (int p = bbase + tid; p < bend; p += 512) {
        uint32 pr = pairs[p];
        int pos = bbase + atomicAdd(&cnt[pr >> 16], 1);
        csr[pos] = (u16)pr;
    }
}

// ---- node kernel: one BLOCK per node (3 waves, wave h = hop-list 3n+h).
//      NEW layout: 16 lanes/edge, uint4 (8 bf16)/lane; 4 chains x 4 edges = 16
//      edges/iter. Logit reduce = 2 exact quad-perm DPP adds. Tail = masked
//      2-chain 8-edge passes. Epilogue: exact swizzle/shfl reductions. --------
// lane = 16*q + m: q = edge slot (0..3), m = feature group; lane m holds
// features 8m..8m+7 -> head h = m>>2, channels c = 8*(m&3)+j.
#define NH_CHAIN(cv, wv_)                                              \
    {                                                                  \
        float lx[8] = {bflo(cv.x), bfhij(cv.x), bflo(cv.y), bfhij(cv.y), \
                       bflo(cv.z), bfhij(cv.z), bflo(cv.w), bfhij(cv.w)}; \
        float p = 0.f;                                                 \
        _Pragma("unroll")                                              \
        for (int j = 0; j < 8; ++j) {                                  \
            float g_ = lx[j] + rr[j];                                  \
            p = fmaf(a6[j], g_, p);                                    \
            p = fmaf(a4[j], fabsf(g_), p);                             \
        }                                                              \
        p = dppadd<0xB1>(p);                                           \
        p = dppadd<0x4E>(p);                                           \
        wv_ = EXP2F(p);                                                \
        lx0_ = lx[0]; lx1_ = lx[1]; lx2_ = lx[2]; lx3_ = lx[3];        \
        lx4_ = lx[4]; lx5_ = lx[5]; lx6_ = lx[6]; lx7_ = lx[7];        \
    }
#define NH_ACCUM(wv_)                                                  \
    {                                                                  \
        d += wv_;                                                      \
        acc[0] = fmaf(wv_, lx0_, acc[0]);                              \
        acc[1] = fmaf(wv_, lx1_, acc[1]);                              \
        acc[2] = fmaf(wv_, lx2_, acc[2]);                              \
        acc[3] = fmaf(wv_, lx3_, acc[3]);                              \
        acc[4] = fmaf(wv_, lx4_, acc[4]);                              \
        acc[5] = fmaf(wv_, lx5_, acc[5]);                              \
        acc[6] = fmaf(wv_, lx6_, acc[6]);                              \
        acc[7] = fmaf(wv_, lx7_, acc[7]);                              \
    }
__global__ __launch_bounds__(192) void node_hop(
    const uint4* __restrict__ xlv,   // [N*16], uint4 = 8 bf16
    const uint4* __restrict__ xrv,   // [N*16], uint4 = 8 bf16
    const u16* __restrict__ csr,     // [T + 16] (pad; junk values land inside ws)
    const int* __restrict__ offsets, // [M+1]
    const float* __restrict__ att,   // [3*128]
    const float* __restrict__ bias,  // [3*32]
    const float* __restrict__ gate4, // [N*4]
    float* __restrict__ out,         // [N*32]
    int N, int M)
{
    const float L2E = 1.44269504088896f;
    __shared__ float4 smsg[3][8];
    int n = blockIdx.x;
    int h = threadIdx.x >> 6;        // wave = hop
    int lane = threadIdx.x & 63;
    int i = 3 * n + h;
    int q = lane >> 4, m = lane & 15;

    uint4 rv = xrv[(size_t)n * 16 + m];
    float rr[8] = {bflo(rv.x), bfhij(rv.x), bflo(rv.y), bfhij(rv.y),
                   bflo(rv.z), bfhij(rv.z), bflo(rv.w), bfhij(rv.w)};
    float4 aA = ((const float4*)(att + h * 128))[2 * m];
    float4 aB = ((const float4*)(att + h * 128))[2 * m + 1];
    float av[8] = {aA.x, aA.y, aA.z, aA.w, aB.x, aB.y, aB.z, aB.w};
    float a6[8], a4[8];
#pragma unroll
    for (int j = 0; j < 8; ++j) {
        a6[j] = 0.6f * L2E * av[j];   // leaky fold: a*leaky(g) = (.6a)g + (.4a)|g|
        a4[j] = 0.4f * L2E * av[j];
    }
    int beg = offsets[i];
    int end = offsets[i + 1];

    float d = 0.f;
    float acc[8];
#pragma unroll
    for (int j = 0; j < 8; ++j) acc[j] = 0.f;
    float lx0_, lx1_, lx2_, lx3_, lx4_, lx5_, lx6_, lx7_;
    int e = beg;
    // 16-edge main loop: 4 chains, each 4 edges (16 lanes/edge); prefetch 16 ahead
    if (e + 16 <= end) {
        int sA = csr[e + q];
        int sB = csr[e + 4 + q];
        int sC = csr[e + 8 + q];
        int sD = csr[e + 12 + q];
        uint4 lvA = xlv[sA * 16 + m];
        uint4 lvB = xlv[sB * 16 + m];
        uint4 lvC = xlv[sC * 16 + m];
        uint4 lvD = xlv[sD * 16 + m];
        for (; e + 16 <= end; e += 16) {
            uint4 cvA = lvA, cvB = lvB, cvC = lvC, cvD = lvD;
            sA = csr[e + 16 + q];
            sB = csr[e + 20 + q];
            sC = csr[e + 24 + q];
            sD = csr[e + 28 + q];   // max idx end+15 -> csr pad 16 covers it
            lvA = xlv[sA * 16 + m];
            lvB = xlv[sB * 16 + m];
            lvC = xlv[sC * 16 + m];
            lvD = xlv[sD * 16 + m];
            float wvv;
            NH_CHAIN(cvA, wvv); NH_ACCUM(wvv);
            NH_CHAIN(cvB, wvv); NH_ACCUM(wvv);
            NH_CHAIN(cvC, wvv); NH_ACCUM(wvv);
            NH_CHAIN(cvD, wvv); NH_ACCUM(wvv);
        }
    }
    // masked 8-edge tail passes (2 chains, clamped re-load keeps NaN out)
    for (; e < end; e += 8) {
        int e1i = end - 1;
        int s1 = csr[min(e + q, e1i)];
        int s2 = csr[min(e + 4 + q, e1i)];
        uint4 cvA = xlv[s1 * 16 + m];
        uint4 cvB = xlv[s2 * 16 + m];
        bool vA = (e + q) < end;
        bool vB = (e + 4 + q) < end;
        float wvv;
        NH_CHAIN(cvA, wvv);
        wvv = vA ? wvv : 0.f;
        NH_ACCUM(wvv);
        NH_CHAIN(cvB, wvv);
        wvv = vB ? wvv : 0.f;
        NH_ACCUM(wvv);
    }
    // combine the 4 edge slots (q = lane bits 4,5): exact xor16 swizzle + shfl32
    d += swz<0x401F>(d);  d += __shfl_xor(d, 32);
#pragma unroll
    for (int j = 0; j < 8; ++j) {
        acc[j] += swz<0x401F>(acc[j]);
        acc[j] += __shfl_xor(acc[j], 32);
    }
    float inv = (d > 0.f) ? (1.0f / d) : 0.f;  // deg==0 -> msg = bias
    // normalize, then head-mean over m>>2 (exact xor4 + xor8 swizzles)
    float qv[8];
#pragma unroll
    for (int j = 0; j < 8; ++j) {
        qv[j] = acc[j] * inv;
        qv[j] += swz<0x101F>(qv[j]);   // xor4
        qv[j] += swz<0x201F>(qv[j]);   // xor8
    }
    if (lane < 4) {
        const float4* bp = (const float4*)(bias + h * 32);
        float4 b1 = bp[2 * lane], b2 = bp[2 * lane + 1];
        smsg[h][2 * lane] = make_float4(
            fmaf(qv[0], 0.25f, b1.x), fmaf(qv[1], 0.25f, b1.y),
            fmaf(qv[2], 0.25f, b1.z), fmaf(qv[3], 0.25f, b1.w));
        smsg[h][2 * lane + 1] = make_float4(
            fmaf(qv[4], 0.25f, b2.x), fmaf(qv[5], 0.25f, b2.y),
            fmaf(qv[6], 0.25f, b2.z), fmaf(qv[7], 0.25f, b2.w));
    }
    __syncthreads();
    if (threadIdx.x < 8) {
        int c = threadIdx.x;
        float4 g = ((const float4*)gate4)[n];
        float4 m0 = smsg[0][c], m1 = smsg[1][c], m2 = smsg[2][c];
        float4 o;
        o.x = g.x * m0.x + g.y * m1.x + g.z * m2.x;
        o.y = g.x * m0.y + g.y * m1.y + g.z * m2.y;
        o.z = g.x * m0.z + g.y * m1.z + g.z * m2.z;
        o.w = g.x * m0.w + g.y * m1.w + g.z * m2.w;
        ((float4*)(out + (size_t)n * 32))[c] = o;
    }
}

// ---------------- launch ----------------
extern "C" void kernel_launch(void* const* d_in, const int* in_sizes, int n_in,
                              void* d_out, int out_size, void* d_ws, size_t ws_size,
                              hipStream_t stream) {
    const float* x  = (const float*)d_in[0];
    const int* e0 = (const int*)d_in[1];
    const int* e1 = (const int*)d_in[2];
    const int* e2 = (const int*)d_in[3];
    const float* wl = (const float*)d_in[4];
    const float* bl = (const float*)d_in[5];
    const float* wr = (const float*)d_in[6];
    const float* br = (const float*)d_in[7];
    const float* att = (const float*)d_in[8];
    const float* cb  = (const float*)d_in[9];
    const float* gw  = (const float*)d_in[10];
    const float* gb  = (const float*)d_in[11];

    int N = in_sizes[0] / 128;
    int E = in_sizes[1] / 2;
    float* out = (float*)d_out;

    int M = 3 * N;                        // 150000 lists (dst*3+hop)
    int T = 3 * E + N;                    // 2450000 entries incl. self-loops
    int NBUCK = (N + 127) >> 7;           // 391 buckets of 128 dsts
    int NBLKA = (T + CHUNK - 1) / CHUNK;  // 300 pass-A chunks
    int MH = NBUCK * NBLKA;               // 117300 hist entries

    char* ws = (char*)d_ws;
    u16* xl      = (u16*)ws;   ws += (size_t)N * 128 * 2;
    u16* xr      = (u16*)ws;   ws += (size_t)N * 128 * 2;
    float* gate4 = (float*)ws; ws += (size_t)N * 4 * 4;
    int* offsets  = (int*)ws; ws += (size_t)(M + 1) * 4;
    int* hist     = (int*)ws; ws += (size_t)MH * 4;
    int* histS    = (int*)ws; ws += (size_t)MH * 4;
    int* partials = (int*)ws; ws += 4096;
    u16* csr_src  = (u16*)ws; ws += (size_t)(T + 16) * 2;
    u16* wfrag    = (u16*)ws; ws += (size_t)16 * 4 * 64 * 8 * 2;  // 64KB
    uint32* pairs = (uint32*)(((uintptr_t)ws + 63) & ~(uintptr_t)63);

    int LB = (N + LROWS - 1) / LROWS;
    wprep<<<16, 256, 0, stream>>>(wl, wr, wfrag);
    fused_pre<<<LB + NBLKA, 256, 0, stream>>>(x, wfrag, bl, br, gw, gb, xl, xr, gate4,
                                              e0, e1, e2, hist, N, E, T, LB, NBUCK);
    int GH = (MH + 1023) / 1024;
    scan1h<<<GH, 1024, 0, stream>>>(hist, MH, NBLKA, NBUCK, histS, partials);
    scan2<<<1, 1024, 0, stream>>>(partials, GH);
    passA2<<<NBLKA, 512, 0, stream>>>(e0, e1, e2, E, T, NBLKA, NBUCK,
                                      hist, histS, partials, pairs);
    passB<<<NBUCK, 512, 0, stream>>>(pairs, histS, partials, csr_src, offsets,
                                     T, M, NBLKA, NBUCK);
    node_hop<<<N, 192, 0, stream>>>(
        (const uint4*)xl, (const uint4*)xr, csr_src, offsets, att, cb, gate4, out, N, M);
}

// Round 20
// 171.859 us; speedup vs baseline: 1.0453x; 1.0453x over previous
//
#include <hip/hip_runtime.h>
#include <math.h>

typedef unsigned int uint32;
typedef unsigned short u16;

#if __has_builtin(__builtin_amdgcn_exp2f)
#define EXP2F(x) __builtin_amdgcn_exp2f(x)
#else
#define EXP2F(x) exp2f(x)
#endif

#define LROWS 64            // rows per linear block (4 waves x 16)
#define CHUNK 8192
#define CHUNK_SHIFT 13
#define NBUCK_MAX 512       // >= (N+127)>>7
#define LPB 384             // lists per bucket = 128 dsts * 3 hops

typedef __attribute__((ext_vector_type(8))) short bf16x8;
typedef __attribute__((ext_vector_type(4))) float f32x4;

__device__ __forceinline__ u16 f2bf(float f) {  // RNE
    uint32 u = __float_as_uint(f);
    u += 0x7fffu + ((u >> 16) & 1u);
    return (u16)(u >> 16);
}
__device__ __forceinline__ float bflo(uint32 v) { return __uint_as_float(v << 16); }
// hi bf16 with junk low mantissa bits: rel err < 2^-16, exponent untouched (no NaN/Inf)
__device__ __forceinline__ float bfhij(uint32 v) { return __uint_as_float(v); }

template<int PAT>
__device__ __forceinline__ float swz(float v) {  // ds_swizzle xor within 32 lanes
    return __int_as_float(__builtin_amdgcn_ds_swizzle(__float_as_int(v), PAT));
}
// DPP-fused cross-lane add (valid ONLY when the fetched value is homogeneous
// within the mirrored subgroup, or the pairing is an exact xor):
// 0xB1=quad_perm[1,0,3,2] -> exact xor1; 0x4E=quad_perm[2,3,0,1] -> exact xor2;
// 0x141=row_half_mirror -> xor4 substitute ONLY after xor1+xor2.
// NOT valid for the epilogue head-sum (per-lane distinct values).
template<int CTRL>
__device__ __forceinline__ float dppadd(float v) {
    int r = __builtin_amdgcn_update_dpp(0, __float_as_int(v), CTRL, 0xF, 0xF, true);
    return v + __int_as_float(r);
}

// decode edge t -> (hop, src, dst); synthetic t>=3E are hop-0 self-loops
__device__ __forceinline__ void edge_decode(
    int t, int E, const int* __restrict__ e0, const int* __restrict__ e1,
    const int* __restrict__ e2, int& hop, int& src, int& dst)
{
    if (t < E)          { hop = 0; src = e0[t];         dst = e0[E + t]; }
    else if (t < 2 * E) { hop = 1; src = e1[t - E];     dst = e1[t]; }
    else if (t < 3 * E) { hop = 2; src = e2[t - 2 * E]; dst = e2[t - E]; }
    else                { hop = 0; src = t - 3 * E;     dst = src; }
}

// ---- wprep: permute [wl|wr] into MFMA B-fragment order, bf16 -----------------
__global__ __launch_bounds__(256) void wprep(
    const float* __restrict__ wl, const float* __restrict__ wr, u16* __restrict__ wfrag)
{
    int ct = blockIdx.x;            // 0..15 col-tile
    int ks = threadIdx.x >> 6;      // 0..3 K-step
    int lane = threadIdx.x & 63;
    int g = lane >> 4, rr = lane & 15;
    int c = ct * 16 + rr;
    const float* w = (c < 128) ? wl : wr;
    int cc = c & 127;
    u16* o = wfrag + (((size_t)ct * 4 + ks) * 64 + lane) * 8;
#pragma unroll
    for (int i = 0; i < 8; ++i) {
        int k = ks * 32 + g * 4 + (i & 3) + ((i >> 2) << 4);
        o[i] = f2bf(w[k * 128 + cc]);
    }
}

// ---- fused: [0,LB) MFMA-linear+gate blocks; [LB,LB+NBLKA) bucket-hist blocks -
__global__ __launch_bounds__(256) void fused_pre(
    const float* __restrict__ x, const u16* __restrict__ wfrag,
    const float* __restrict__ bl, const float* __restrict__ br,
    const float* __restrict__ gw, const float* __restrict__ gb,
    u16* __restrict__ xl, u16* __restrict__ xr, float* __restrict__ gate4,
    const int* __restrict__ e0, const int* __restrict__ e1, const int* __restrict__ e2,
    int* __restrict__ hist,
    int N, int E, int T, int LB, int NBUCK)
{
    __shared__ float4 sx[LROWS][32];
    __shared__ float gbuf[LROWS][3];
    __shared__ int lhist[NBUCK_MAX];

    if ((int)blockIdx.x >= LB) {                 // ---- pass A1: pure bucket histogram
        int blk = (int)blockIdx.x - LB;
        int t0 = blk << CHUNK_SHIFT;
        for (int j = threadIdx.x; j < NBUCK; j += 256) lhist[j] = 0;
        __syncthreads();
        for (int it = 0; it < CHUNK / 256; ++it) {
            int t = t0 + it * 256 + (int)threadIdx.x;
            if (t < T) {
                int dst;
                if (t < E)          dst = e0[E + t];
                else if (t < 2 * E) dst = e1[t];
                else if (t < 3 * E) dst = e2[t - E];
                else                dst = t - 3 * E;
                atomicAdd(&lhist[dst >> 7], 1);  // non-returning -> ds_add
            }
        }
        __syncthreads();
        for (int j = threadIdx.x; j < NBUCK; j += 256)
            hist[(size_t)blk * NBUCK + j] = lhist[j];
        return;
    }
    // ---- linear via MFMA + gate ----
    int t = threadIdx.x;
    int r0 = blockIdx.x * LROWS;
    int nr = min(LROWS, N - r0);
    {
        const float4* xi = (const float4*)(x + (size_t)r0 * 128);
        for (int i = t; i < nr * 32; i += 256) ((float4*)sx)[i] = xi[i];
    }
    __syncthreads();
    int wv = t >> 6, lane = t & 63;
    int g = lane >> 4, rr = lane & 15;
    // A fragments: row = wv*16 + (lane&15)  [m89-verified M mapping]
    bf16x8 afr[4];
    {
        const float4* xrow = sx[wv * 16 + rr];
#pragma unroll
        for (int ks = 0; ks < 4; ++ks) {
            float4 u = xrow[ks * 8 + g];       // k = ks*32 + g*4 + 0..3
            float4 v = xrow[ks * 8 + 4 + g];   // k = ks*32 + 16 + g*4 + 0..3
            union { u16 h[8]; bf16x8 v8; } pk;
            pk.h[0] = f2bf(u.x); pk.h[1] = f2bf(u.y);
            pk.h[2] = f2bf(u.z); pk.h[3] = f2bf(u.w);
            pk.h[4] = f2bf(v.x); pk.h[5] = f2bf(v.y);
            pk.h[6] = f2bf(v.z); pk.h[7] = f2bf(v.w);
            afr[ks] = pk.v8;
        }
    }
    const bf16x8* wfp = (const bf16x8*)wfrag;
    for (int ct = 0; ct < 16; ++ct) {
        f32x4 acc = {0.f, 0.f, 0.f, 0.f};
#pragma unroll
        for (int ks = 0; ks < 4; ++ks) {
            bf16x8 bf = wfp[((ct * 4 + ks) << 6) + lane];
            acc = __builtin_amdgcn_mfma_f32_16x16x32_bf16(afr[ks], bf, acc, 0, 0, 0);
        }
        int c = ct * 16 + rr;
        float bv = (ct < 8) ? bl[c] : br[c - 128];
        u16* ob = (ct < 8) ? xl : xr;
        int cc = c & 127;
#pragma unroll
        for (int i = 0; i < 4; ++i) {          // D: row=(lane>>4)*4+i, col=lane&15
            int row = wv * 16 + g * 4 + i;
            if (row < nr)
                ob[(size_t)(r0 + row) * 128 + cc] = f2bf(acc[i] + bv);
        }
    }
    // gate (fp32 from LDS, unchanged)
    if (t < nr * 3) {
        int r = t / 3, k = t - 3 * r;
        float s = 0.f;
        const float4* xrow = sx[r];
#pragma unroll 4
        for (int i = 0; i < 32; ++i) {
            float4 v = xrow[i];
            s += v.x * gw[(4 * i + 0) * 3 + k] + v.y * gw[(4 * i + 1) * 3 + k]
               + v.z * gw[(4 * i + 2) * 3 + k] + v.w * gw[(4 * i + 3) * 3 + k];
        }
        gbuf[r][k] = s + gb[k];
    }
    __syncthreads();
    if (t < nr) {
        float s0 = gbuf[t][0], s1 = gbuf[t][1], s2 = gbuf[t][2];
        float mx = fmaxf(s0, fmaxf(s1, s2));
        float e0v = __expf(s0 - mx), e1v = __expf(s1 - mx), e2v = __expf(s2 - mx);
        float inv = 1.f / (e0v + e1v + e2v);
        *(float4*)(gate4 + (size_t)(r0 + t) * 4) = make_float4(e0v * inv, e1v * inv, e2v * inv, 0.f);
    }
}

// ---- scans over hist in bin-major order (i -> (bin=i/NBLKA, blk=i%NBLKA)) ----
__global__ __launch_bounds__(1024) void scan1h(const int* __restrict__ hist, int MH,
                                               int NBLKA, int NBUCK,
                                               int* __restrict__ histS, int* __restrict__ partials) {
    __shared__ int s[1024];
    int t = threadIdx.x;
    int i = blockIdx.x * 1024 + t;
    int v = 0;
    if (i < MH) {
        int bin = (int)((uint32)i / (uint32)NBLKA);
        int blk = i - bin * NBLKA;
        v = hist[(size_t)blk * NBUCK + bin];
    }
    s[t] = v;
    __syncthreads();
    for (int o = 1; o < 1024; o <<= 1) {
        int u = (t >= o) ? s[t - o] : 0;
        __syncthreads();
        s[t] += u;
        __syncthreads();
    }
    if (i < MH) histS[i] = s[t] - v;
    if (t == 1023) partials[blockIdx.x] = s[1023];
}

__global__ __launch_bounds__(1024) void scan2(int* __restrict__ partials, int G) {
    __shared__ int s[1024];
    int t = threadIdx.x;
    int v = (t < G) ? partials[t] : 0;
    s[t] = v;
    __syncthreads();
    for (int o = 1; o < 1024; o <<= 1) {
        int u = (t >= o) ? s[t - o] : 0;
        __syncthreads();
        s[t] += u;
        __syncthreads();
    }
    if (t < G) partials[t] = s[t] - v;
}

// ---- pass A2: LDS-stage chunk sorted by bucket (self-ranked), coalesced flush -
__global__ __launch_bounds__(512) void passA2(
    const int* __restrict__ e0, const int* __restrict__ e1, const int* __restrict__ e2,
    int E, int T, int NBLKA, int NBUCK,
    const int* __restrict__ hist, const int* __restrict__ histS,
    const int* __restrict__ partials,
    uint32* __restrict__ pairs)
{
    __shared__ int lscan[512];
    __shared__ int gbase[512];
    __shared__ uint32 lp[CHUNK];
    __shared__ u16 lb[CHUNK];
    int blk = blockIdx.x, tid = threadIdx.x;
    int t0 = blk << CHUNK_SHIFT;
    int vc = min(CHUNK, T - t0);
    int c = (tid < NBUCK) ? hist[(size_t)blk * NBUCK + tid] : 0;
    lscan[tid] = c;
    __syncthreads();
    for (int o = 1; o < 512; o <<= 1) {
        int u = (tid >= o) ? lscan[tid - o] : 0;
        __syncthreads();
        lscan[tid] += u;
        __syncthreads();
    }
    int excl = lscan[tid] - c;
    lscan[tid] = excl;                    // becomes the placement cursor
    if (tid < NBUCK) {
        int k = tid * NBLKA + blk;
        gbase[tid] = histS[k] + partials[k >> 10] - excl;
    }
    __syncthreads();
    for (int it = 0; it < CHUNK / 512; ++it) {
        int t = t0 + it * 512 + tid;
        if (t < T) {
            int hop, src, dst;
            edge_decode(t, E, e0, e1, e2, hop, src, dst);
            int bin = dst >> 7;
            int j = atomicAdd(&lscan[bin], 1);   // self-rank (order need not match A1)
            lp[j] = (uint32)src | ((uint32)((dst & 127) * 3 + hop) << 16);
            lb[j] = (u16)bin;
        }
    }
    __syncthreads();
    for (int j = tid; j < vc; j += 512)
        pairs[gbase[lb[j]] + j] = lp[j];
}

// ---- pass B: per-bucket counting sort -> offsets + csr (LDS atomics only) ----
__global__ __launch_bounds__(512) void passB(
    const uint32* __restrict__ pairs, const int* __restrict__ histS,
    const int* __restrict__ partials, u16* __restrict__ csr, int* __restrict__ offsets,
    int T, int M, int NBLKA, int NBUCK) {
    __shared__ int cnt[LPB];
    __shared__ int scn[512];
    int b = blockIdx.x;
    int tid = threadIdx.x;
    int k0 = b * NBLKA;
    int bbase = histS[k0] + partials[k0 >> 10];
    int bend;
    if (b == NBUCK - 1) bend = T;
    else { int k1 = k0 + NBLKA; bend = histS[k1] + partials[k1 >> 10]; }
    if (b == 0 && tid == 0) offsets[M] = T;

    if (tid < LPB) cnt[tid] = 0;
    __syncthreads();
    for (int p = bbase + tid; p < bend; p += 512)
        atomicAdd(&cnt[pairs[p] >> 16], 1);
    __syncthreads();
    int c = (tid < LPB) ? cnt[tid] : 0;
    scn[tid] = c;
    __syncthreads();
    for (int o = 1; o < 512; o <<= 1) {
        int u = (tid >= o) ? scn[tid - o] : 0;
        __syncthreads();
        scn[tid] += u;
        __syncthreads();
    }
    int excl = scn[tid] - c;
    int nlists = min(LPB, M - b * LPB);
    if (tid < nlists) offsets[b * LPB + tid] = bbase + excl;
    __syncthreads();
    if (tid < LPB) cnt[tid] = excl;          // cursor
    __syncthreads();
    for (int p = bbase + tid; p < bend; p += 512) {
        uint32 pr = pairs[p];
        int pos = bbase + atomicAdd(&cnt[pr >> 16], 1);
        csr[pos] = (u16)pr;
    }
}

// ---- node kernel: one BLOCK per node (3 waves, wave h = hop-list 3n+h);
//      32-lane / 4-chain / 8-edge loop; DPP logit reduce (main loop only);
//      EXACT swizzle for epilogue head-sum; gate-combine in LDS ---------------
__global__ __launch_bounds__(192) void node_hop(
    const uint2* __restrict__ xlv,   // [N*32], uint2 = 4 bf16
    const uint2* __restrict__ xrv,   // [N*32], uint2 = 4 bf16
    const u16* __restrict__ csr,     // [T + 16] (pad; junk values OK)
    const int* __restrict__ offsets, // [M+1]
    const float* __restrict__ att,   // [3*128]
    const float* __restrict__ bias,  // [3*32]
    const float* __restrict__ gate4, // [N*4]
    float* __restrict__ out,         // [N*32]
    int N, int M)
{
    const float L2E = 1.44269504088896f;
    __shared__ float4 smsg[3][8];
    int n = blockIdx.x;
    int h = threadIdx.x >> 6;        // wave = hop
    int lane = threadIdx.x & 63;
    int i = 3 * n + h;
    int half = lane >> 5, l5 = lane & 31;

    uint2 rv = xrv[(size_t)n * 32 + l5];
    float4 r4;
    r4.x = bflo(rv.x); r4.y = bfhij(rv.x);
    r4.z = bflo(rv.y); r4.w = bfhij(rv.y);
    float4 a4 = ((const float4*)(att + h * 128))[l5];
    // fold leaky into att: a*leaky(g) = (0.6a)g + (0.4a)|g| ; fold log2e too
    float a6x = 0.6f * L2E * a4.x, a6y = 0.6f * L2E * a4.y;
    float a6z = 0.6f * L2E * a4.z, a6w = 0.6f * L2E * a4.w;
    float a4x = 0.4f * L2E * a4.x, a4y = 0.4f * L2E * a4.y;
    float a4z = 0.4f * L2E * a4.z, a4w = 0.4f * L2E * a4.w;
    int beg = offsets[i];
    int end = offsets[i + 1];

    float d = 0.f, acc0 = 0.f, acc1 = 0.f, acc2 = 0.f, acc3 = 0.f;
    int e = beg;
    // 8-edge main loop: 4 chains (A..D), prefetch 8 ahead (csr pad-safe)
    if (e + 8 <= end) {
        int sA = csr[e + half];
        int sB = csr[e + 2 + half];
        int sC = csr[e + 4 + half];
        int sD = csr[e + 6 + half];
        uint2 lvA = xlv[sA * 32 + l5];
        uint2 lvB = xlv[sB * 32 + l5];
        uint2 lvC = xlv[sC * 32 + l5];
        uint2 lvD = xlv[sD * 32 + l5];
        for (; e + 8 <= end; e += 8) {
            uint2 cvA = lvA, cvB = lvB, cvC = lvC, cvD = lvD;
            sA = csr[e + 8 + half];
            sB = csr[e + 10 + half];
            sC = csr[e + 12 + half];
            sD = csr[e + 14 + half];
            lvA = xlv[sA * 32 + l5];
            lvB = xlv[sB * 32 + l5];
            lvC = xlv[sC * 32 + l5];
            lvD = xlv[sD * 32 + l5];
            float lxA0 = bflo(cvA.x), lxA1 = bfhij(cvA.x);
            float lxA2 = bflo(cvA.y), lxA3 = bfhij(cvA.y);
            float lxB0 = bflo(cvB.x), lxB1 = bfhij(cvB.x);
            float lxB2 = bflo(cvB.y), lxB3 = bfhij(cvB.y);
            float lxC0 = bflo(cvC.x), lxC1 = bfhij(cvC.x);
            float lxC2 = bflo(cvC.y), lxC3 = bfhij(cvC.y);
            float lxD0 = bflo(cvD.x), lxD1 = bfhij(cvD.x);
            float lxD2 = bflo(cvD.y), lxD3 = bfhij(cvD.y);
            float gA0 = lxA0 + r4.x, gA1 = lxA1 + r4.y, gA2 = lxA2 + r4.z, gA3 = lxA3 + r4.w;
            float gB0 = lxB0 + r4.x, gB1 = lxB1 + r4.y, gB2 = lxB2 + r4.z, gB3 = lxB3 + r4.w;
            float gC0 = lxC0 + r4.x, gC1 = lxC1 + r4.y, gC2 = lxC2 + r4.z, gC3 = lxC3 + r4.w;
            float gD0 = lxD0 + r4.x, gD1 = lxD1 + r4.y, gD2 = lxD2 + r4.z, gD3 = lxD3 + r4.w;
            float pA = a6x * gA0;
            pA = fmaf(a4x, fabsf(gA0), pA);
            pA = fmaf(a6y, gA1, pA);
            pA = fmaf(a4y, fabsf(gA1), pA);
            pA = fmaf(a6z, gA2, pA);
            pA = fmaf(a4z, fabsf(gA2), pA);
            pA = fmaf(a6w, gA3, pA);
            pA = fmaf(a4w, fabsf(gA3), pA);
            float pB = a6x * gB0;
            pB = fmaf(a4x, fabsf(gB0), pB);
            pB = fmaf(a6y, gB1, pB);
            pB = fmaf(a4y, fabsf(gB1), pB);
            pB = fmaf(a6z, gB2, pB);
            pB = fmaf(a4z, fabsf(gB2), pB);
            pB = fmaf(a6w, gB3, pB);
            pB = fmaf(a4w, fabsf(gB3), pB);
            float pC = a6x * gC0;
            pC = fmaf(a4x, fabsf(gC0), pC);
            pC = fmaf(a6y, gC1, pC);
            pC = fmaf(a4y, fabsf(gC1), pC);
            pC = fmaf(a6z, gC2, pC);
            pC = fmaf(a4z, fabsf(gC2), pC);
            pC = fmaf(a6w, gC3, pC);
            pC = fmaf(a4w, fabsf(gC3), pC);
            float pD = a6x * gD0;
            pD = fmaf(a4x, fabsf(gD0), pD);
            pD = fmaf(a6y, gD1, pD);
            pD = fmaf(a4y, fabsf(gD1), pD);
            pD = fmaf(a6z, gD2, pD);
            pD = fmaf(a4z, fabsf(gD2), pD);
            pD = fmaf(a6w, gD3, pD);
            pD = fmaf(a4w, fabsf(gD3), pD);
            pA = dppadd<0xB1>(pA);  pB = dppadd<0xB1>(pB);
            pC = dppadd<0xB1>(pC);  pD = dppadd<0xB1>(pD);
            pA = dppadd<0x4E>(pA);  pB = dppadd<0x4E>(pB);
            pC = dppadd<0x4E>(pC);  pD = dppadd<0x4E>(pD);
            pA = dppadd<0x141>(pA); pB = dppadd<0x141>(pB);
            pC = dppadd<0x141>(pC); pD = dppadd<0x141>(pD);
            float wvA = EXP2F(pA);
            float wvB = EXP2F(pB);
            float wvC = EXP2F(pC);
            float wvD = EXP2F(pD);
            d += (wvA + wvB) + (wvC + wvD);
            acc0 = fmaf(wvA, lxA0, acc0);
            acc1 = fmaf(wvA, lxA1, acc1);
            acc2 = fmaf(wvA, lxA2, acc2);
            acc3 = fmaf(wvA, lxA3, acc3);
            acc0 = fmaf(wvB, lxB0, acc0);
            acc1 = fmaf(wvB, lxB1, acc1);
            acc2 = fmaf(wvB, lxB2, acc2);
            acc3 = fmaf(wvB, lxB3, acc3);
            acc0 = fmaf(wvC, lxC0, acc0);
            acc1 = fmaf(wvC, lxC1, acc1);
            acc2 = fmaf(wvC, lxC2, acc2);
            acc3 = fmaf(wvC, lxC3, acc3);
            acc0 = fmaf(wvD, lxD0, acc0);
            acc1 = fmaf(wvD, lxD1, acc1);
            acc2 = fmaf(wvD, lxD2, acc2);
            acc3 = fmaf(wvD, lxD3, acc3);
        }
    }
    // masked 4-edge tail blocks (rem 0..7 -> up to 2 passes; clamped re-load)
    for (; e < end; e += 4) {
        int e1i = end - 1;
        int s1 = csr[min(e + half, e1i)];
        int s2 = csr[min(e + 2 + half, e1i)];
        uint2 cvA = xlv[s1 * 32 + l5];
        uint2 cvB = xlv[s2 * 32 + l5];
        bool vA = (e + half) < end;
        bool vB = (e + 2 + half) < end;
        float lxA0 = bflo(cvA.x), lxA1 = bfhij(cvA.x);
        float lxA2 = bflo(cvA.y), lxA3 = bfhij(cvA.y);
        float lxB0 = bflo(cvB.x), lxB1 = bfhij(cvB.x);
        float lxB2 = bflo(cvB.y), lxB3 = bfhij(cvB.y);
        float gA0 = lxA0 + r4.x, gA1 = lxA1 + r4.y;
        float gA2 = lxA2 + r4.z, gA3 = lxA3 + r4.w;
        float gB0 = lxB0 + r4.x, gB1 = lxB1 + r4.y;
        float gB2 = lxB2 + r4.z, gB3 = lxB3 + r4.w;
        float pA = a6x * gA0;
        pA = fmaf(a4x, fabsf(gA0), pA);
        pA = fmaf(a6y, gA1, pA);
        pA = fmaf(a4y, fabsf(gA1), pA);
        pA = fmaf(a6z, gA2, pA);
        pA = fmaf(a4z, fabsf(gA2), pA);
        pA = fmaf(a6w, gA3, pA);
        pA = fmaf(a4w, fabsf(gA3), pA);
        float pB = a6x * gB0;
        pB = fmaf(a4x, fabsf(gB0), pB);
        pB = fmaf(a6y, gB1, pB);
        pB = fmaf(a4y, fabsf(gB1), pB);
        pB = fmaf(a6z, gB2, pB);
        pB = fmaf(a4z, fabsf(gB2), pB);
        pB = fmaf(a6w, gB3, pB);
        pB = fmaf(a4w, fabsf(gB3), pB);
        pA = dppadd<0xB1>(pA);
        pB = dppadd<0xB1>(pB);
        pA = dppadd<0x4E>(pA);
        pB = dppadd<0x4E>(pB);
        pA = dppadd<0x141>(pA);
        pB = dppadd<0x141>(pB);
        float wvA = EXP2F(pA);
        float wvB = EXP2F(pB);
        wvA = vA ? wvA : 0.f;
        wvB = vB ? wvB : 0.f;
        d += wvA + wvB;
        acc0 = fmaf(wvA, lxA0, acc0);
        acc1 = fmaf(wvA, lxA1, acc1);
        acc2 = fmaf(wvA, lxA2, acc2);
        acc3 = fmaf(wvA, lxA3, acc3);
        acc0 = fmaf(wvB, lxB0, acc0);
        acc1 = fmaf(wvB, lxB1, acc1);
        acc2 = fmaf(wvB, lxB2, acc2);
        acc3 = fmaf(wvB, lxB3, acc3);
    }
    // combine edge halves (lane bit 5) -- crosses 32-lane boundary, keep shfl
    d += __shfl_xor(d, 32);
    acc0 += __shfl_xor(acc0, 32);
    acc1 += __shfl_xor(acc1, 32);
    acc2 += __shfl_xor(acc2, 32);
    acc3 += __shfl_xor(acc3, 32);
    float inv = (d > 0.f) ? (1.0f / d) : 0.f;  // deg==0 -> msg = bias
    float q0 = acc0 * inv, q1 = acc1 * inv, q2 = acc2 * inv, q3 = acc3 * inv;
    // sum over 4 heads (lane bits 3,4): values are per-lane DISTINCT here,
    // so the permutation must be the EXACT xor -- ds_swizzle, not DPP mirrors.
    q0 += swz<0x201F>(q0);  q0 += swz<0x401F>(q0);
    q1 += swz<0x201F>(q1);  q1 += swz<0x401F>(q1);
    q2 += swz<0x201F>(q2);  q2 += swz<0x401F>(q2);
    q3 += swz<0x201F>(q3);  q3 += swz<0x401F>(q3);
    if (lane < 8) {
        float4 b4 = ((const float4*)(bias + h * 32))[lane];
        smsg[h][lane] = make_float4(fmaf(q0, 0.25f, b4.x), fmaf(q1, 0.25f, b4.y),
                                    fmaf(q2, 0.25f, b4.z), fmaf(q3, 0.25f, b4.w));
    }
    __syncthreads();
    if (threadIdx.x < 8) {
        int c = threadIdx.x;
        float4 g = ((const float4*)gate4)[n];
        float4 m0 = smsg[0][c], m1 = smsg[1][c], m2 = smsg[2][c];
        float4 o;
        o.x = g.x * m0.x + g.y * m1.x + g.z * m2.x;
        o.y = g.x * m0.y + g.y * m1.y + g.z * m2.y;
        o.z = g.x * m0.z + g.y * m1.z + g.z * m2.z;
        o.w = g.x * m0.w + g.y * m1.w + g.z * m2.w;
        ((float4*)(out + (size_t)n * 32))[c] = o;
    }
}

// ---------------- launch ----------------
extern "C" void kernel_launch(void* const* d_in, const int* in_sizes, int n_in,
                              void* d_out, int out_size, void* d_ws, size_t ws_size,
                              hipStream_t stream) {
    const float* x  = (const float*)d_in[0];
    const int* e0 = (const int*)d_in[1];
    const int* e1 = (const int*)d_in[2];
    const int* e2 = (const int*)d_in[3];
    const float* wl = (const float*)d_in[4];
    const float* bl = (const float*)d_in[5];
    const float* wr = (const float*)d_in[6];
    const float* br = (const float*)d_in[7];
    const float* att = (const float*)d_in[8];
    const float* cb  = (const float*)d_in[9];
    const float* gw  = (const float*)d_in[10];
    const float* gb  = (const float*)d_in[11];

    int N = in_sizes[0] / 128;
    int E = in_sizes[1] / 2;
    float* out = (float*)d_out;

    int M = 3 * N;                        // 150000 lists (dst*3+hop)
    int T = 3 * E + N;                    // 2450000 entries incl. self-loops
    int NBUCK = (N + 127) >> 7;           // 391 buckets of 128 dsts
    int NBLKA = (T + CHUNK - 1) / CHUNK;  // 300 pass-A chunks
    int MH = NBUCK * NBLKA;               // 117300 hist entries

    char* ws = (char*)d_ws;
    u16* xl      = (u16*)ws;   ws += (size_t)N * 128 * 2;
    u16* xr      = (u16*)ws;   ws += (size_t)N * 128 * 2;
    float* gate4 = (float*)ws; ws += (size_t)N * 4 * 4;
    int* offsets  = (int*)ws; ws += (size_t)(M + 1) * 4;
    int* hist     = (int*)ws; ws += (size_t)MH * 4;
    int* histS    = (int*)ws; ws += (size_t)MH * 4;
    int* partials = (int*)ws; ws += 4096;
    u16* csr_src  = (u16*)ws; ws += (size_t)(T + 16) * 2;
    u16* wfrag    = (u16*)ws; ws += (size_t)16 * 4 * 64 * 8 * 2;  // 64KB
    uint32* pairs = (uint32*)(((uintptr_t)ws + 63) & ~(uintptr_t)63);

    int LB = (N + LROWS - 1) / LROWS;
    wprep<<<16, 256, 0, stream>>>(wl, wr, wfrag);
    fused_pre<<<LB + NBLKA, 256, 0, stream>>>(x, wfrag, bl, br, gw, gb, xl, xr, gate4,
                                              e0, e1, e2, hist, N, E, T, LB, NBUCK);
    int GH = (MH + 1023) / 1024;
    scan1h<<<GH, 1024, 0, stream>>>(hist, MH, NBLKA, NBUCK, histS, partials);
    scan2<<<1, 1024, 0, stream>>>(partials, GH);
    passA2<<<NBLKA, 512, 0, stream>>>(e0, e1, e2, E, T, NBLKA, NBUCK,
                                      hist, histS, partials, pairs);
    passB<<<NBUCK, 512, 0, stream>>>(pairs, histS, partials, csr_src, offsets,
                                     T, M, NBLKA, NBUCK);
    node_hop<<<N, 192, 0, stream>>>(
        (const uint2*)xl, (const uint2*)xr, csr_src, offsets, att, cb, gate4, out, N, M);
}